// Round 6
// baseline (153.267 us; speedup 1.0000x reference)
//
#include <hip/hip_runtime.h>
#include <math.h>

typedef float  f32x4  __attribute__((ext_vector_type(4)));
typedef __bf16 bf16x8 __attribute__((ext_vector_type(8)));
typedef __bf16 bf16x4 __attribute__((ext_vector_type(4)));

#define MFMA16(a, b, c) __builtin_amdgcn_mfma_f32_16x16x32_bf16((a), (b), (c), 0, 0, 0)

// tr-read: 64-bit LDS transpose read (4 bf16), literal offset
#define TRR(dst, a, lit)  asm volatile("ds_read_b64_tr_b16 %0, %1 offset:" lit : "=v"(dst) : "v"(a))
#define TRRM(dst, a, lit) asm volatile("ds_read_b64_tr_b16 %0, %1 offset:" lit : "=v"(dst) : "v"(a) : "memory")
#define SHUF8(a, b) __builtin_shufflevector((a), (b), 0, 1, 2, 3, 4, 5, 6, 7)

typedef __attribute__((address_space(3))) unsigned int lds_u32;
typedef __attribute__((address_space(1))) const unsigned int glb_u32;

__device__ __forceinline__ void gload16(const __bf16* g, char* l) {
    __builtin_amdgcn_global_load_lds((glb_u32*)g, (lds_u32*)l, 16, 0, 0);
}

// problem sizes
static constexpr int BATCH = 4;
static constexpr int CH    = 256;
static constexpr int M_TOT = BATCH * 4096;  // 16384

// qkv softmax pre-scale folded into Q: 0.125 * log2(e)
static constexpr float QSCALE = 0.18033688011112042f;

// workspace layout (bytes, 16-aligned)
static constexpr size_t OFF_WQKV  = 0;                              // 196608 bf16
static constexpr size_t OFF_WOUT  = 196608ull * 2;                  // 65536 bf16
static constexpr size_t OFF_STATS = OFF_WOUT + 65536ull * 2;        // 128 float2
static constexpr size_t OFF_HID   = OFF_STATS + 1024;               // attn_out [16384,256] bf16
static constexpr size_t OFF_Q     = OFF_HID + (size_t)M_TOT * CH * 2;
static constexpr size_t OFF_K     = OFF_Q   + (size_t)M_TOT * CH * 2;
static constexpr size_t OFF_V     = OFF_K   + (size_t)M_TOT * CH * 2;

// ---------------------------------------------------------------------------
// 1) fused: GN stats (blocks 0..127) + weight convert/permute (blocks 128..1151)
// ---------------------------------------------------------------------------
__global__ __launch_bounds__(256) void pre_kernel(const float* __restrict__ x,
                                                  float2* __restrict__ stats,
                                                  const float* __restrict__ wq,
                                                  const float* __restrict__ wo,
                                                  __bf16* __restrict__ wqf,
                                                  __bf16* __restrict__ wof) {
    if (blockIdx.x < 128) {
        int bg = blockIdx.x;  // 0..127
        const float4* p = (const float4*)(x + (size_t)bg * 32768);
        float s = 0.f, ss = 0.f;
        for (int i = threadIdx.x; i < 8192; i += 256) {
            float4 v = p[i];
            s  += (v.x + v.y) + (v.z + v.w);
            ss += v.x * v.x + v.y * v.y + v.z * v.z + v.w * v.w;
        }
#pragma unroll
        for (int d = 32; d > 0; d >>= 1) { s += __shfl_down(s, d); ss += __shfl_down(ss, d); }
        __shared__ float sh[8];
        int w = threadIdx.x >> 6, l = threadIdx.x & 63;
        if (l == 0) { sh[w] = s; sh[4 + w] = ss; }
        __syncthreads();
        if (threadIdx.x == 0) {
            float S = sh[0] + sh[1] + sh[2] + sh[3];
            float SS = sh[4] + sh[5] + sh[6] + sh[7];
            float mean = S * (1.f / 32768.f);
            float var  = SS * (1.f / 32768.f) - mean * mean;
            stats[bg] = make_float2(mean, rsqrtf(var + 1e-5f));
        }
    } else {
        int i = (blockIdx.x - 128) * 256 + threadIdx.x;   // 0 .. 262143
        if (i < 196608) {
            int e = i & 7, l = (i >> 3) & 63, kk = (i >> 9) & 7, jt = i >> 12;  // jt 0..47
            int kidx = kk * 32 + ((l >> 4) << 3) + e;
            int n = jt * 16 + (l & 15);
            wqf[i] = (__bf16)wq[kidx * 768 + n];
        } else {
            int i2 = i - 196608;                  // 0 .. 65535
            int e = i2 & 7, l = (i2 >> 3) & 63, kk = (i2 >> 9) & 7, jt = i2 >> 12;  // jt 0..15
            int kidx = kk * 32 + ((l >> 4) << 3) + e;
            int n = jt * 16 + (l & 15);
            wof[i2] = (__bf16)wo[kidx * 256 + n];
        }
    }
}

// ---------------------------------------------------------------------------
// 2) fused GroupNorm + QKV GEMM. grid (256 mt, 3 part). Each block:
//    stage GN'd 64-token x 256-ch A-tile into swizzled LDS (bf16), then
//    GEMM 64x256 output (16 fj) with B-frags streamed from permuted weights.
//    part 0/1/2 = q/k/v; q gets QSCALE folded in.
//    LDS A layout: byte(tok,c) = tok*512 + ((c*2) ^ ((tok&7)<<4))
// ---------------------------------------------------------------------------
__global__ __launch_bounds__(256) void qkv_gn(const float* __restrict__ x,
                                              const float* __restrict__ gamma,
                                              const float* __restrict__ beta,
                                              const float2* __restrict__ stats,
                                              const __bf16* __restrict__ wf,
                                              const float* __restrict__ bqkv,
                                              __bf16* __restrict__ qb,
                                              __bf16* __restrict__ kb,
                                              __bf16* __restrict__ vb) {
    const int mt = blockIdx.x;
    const int p  = blockIdx.y;           // 0=q 1=k 2=v
    const int tid = threadIdx.x;
    const int b  = mt >> 6;
    const int n0 = (mt & 63) * 64;

    __shared__ __attribute__((aligned(16))) char At[64 * 512];  // 32 KB

    // ---- staging: thread owns channel c = tid, streams 64 tokens ----
    {
        const int c = tid;
        float2 st = stats[b * 32 + (c >> 3)];
        float gm = gamma[c] * st.y;
        float bt = beta[c] - st.x * gm;
        const float* xp = x + ((size_t)(b * 256 + c)) * 4096 + n0;
        const unsigned cx = (unsigned)(c * 2);
#pragma unroll
        for (int j4 = 0; j4 < 16; ++j4) {
            float4 vv = *(const float4*)(xp + j4 * 4);
            float pv[4] = {vv.x, vv.y, vv.z, vv.w};
#pragma unroll
            for (int i = 0; i < 4; ++i) {
                int tk = j4 * 4 + i;
                *(__bf16*)(At + tk * 512 + (cx ^ ((tk & 7) << 4))) = (__bf16)(pv[i] * gm + bt);
            }
        }
    }
    __syncthreads();

    // ---- GEMM: wave w owns token rows w*16+lr; 16 fj columns ----
    const int w = tid >> 6, l = tid & 63;
    const int lr = l & 15, lh = l >> 4;
    const int tk = w * 16 + lr;
    f32x4 acc[16];
#pragma unroll
    for (int fj = 0; fj < 16; ++fj) acc[fj] = (f32x4){0.f, 0.f, 0.f, 0.f};

#pragma unroll
    for (int kk = 0; kk < 8; ++kk) {
        bf16x8 a = *(const bf16x8*)(At + tk * 512 + ((kk * 64 + lh * 16) ^ ((tk & 7) << 4)));
#pragma unroll
        for (int fj = 0; fj < 16; ++fj) {
            int jt = (fj >> 2) * 12 + p * 4 + (fj & 3);
            bf16x8 bfr = *(const bf16x8*)(wf + (size_t)(((jt * 8 + kk) * 64 + l) * 8));
            acc[fj] = MFMA16(a, bfr, acc[fj]);
        }
    }

    __bf16* dst = (p == 0) ? qb : (p == 1) ? kb : vb;
    const float sc = (p == 0) ? QSCALE : 1.0f;
#pragma unroll
    for (int fj = 0; fj < 16; ++fj) {
        int h = fj >> 2;
        int dd = (fj & 3) * 16 + lr;
        float bias = bqkv[h * 192 + p * 64 + dd];
#pragma unroll
        for (int r = 0; r < 4; ++r) {
            int n = n0 + w * 16 + lh * 4 + r;
            dst[((size_t)((b * 4 + h) * 4096 + n)) * 64 + dd] = (__bf16)((acc[fj][r] + bias) * sc);
        }
    }
}

// ---------------------------------------------------------------------------
// 3) Flash attention, swapped-operand form with STATIC softmax.
//    grid (64 q-tiles, 16 bh), 4 waves x 16 q-rows. Unrolled x2 over the
//    double buffer so all LDS addresses are loop-invariant.
// ---------------------------------------------------------------------------
__global__ __launch_bounds__(256, 4) void attn_fwd(const __bf16* __restrict__ q,
                                                   const __bf16* __restrict__ k,
                                                   const __bf16* __restrict__ v,
                                                   __bf16* __restrict__ ao) {
    const int bh = blockIdx.y;
    const int q0 = blockIdx.x * 64;
    const int tid = threadIdx.x;
    const int wv = tid >> 6, l = tid & 63;
    const int lr = l & 15, lh = l >> 4;

    __shared__ __attribute__((aligned(16))) char smem[32768];  // K dbuf 16K | V dbuf 16K

    const size_t base = (size_t)bh * (4096 * 64);

    // ---- staging addresses (chunk c = wv*64 + l, and +256) ----
    const int c0 = wv * 64 + l;
    const int rK = c0 >> 3, cbK = l & 7;
    const int gk0 = rK * 64 + (cbK ^ (rK & 7)) * 8;        // elements
    const int gk1 = gk0 + 2048;                             // +32 rows
    const int dt0 = c0 >> 7, kq0 = (c0 >> 3) & 15, klo0 = (l >> 1) & 3, d80 = l & 1;
    const int gv0 = (kq0 * 4 + klo0) * 64 + dt0 * 16 + d80 * 8;
    const int gv1 = gv0 + 32;                               // dt+2
    const int lw0 = wv * 1024;                              // wave-uniform LDS bases
    const int lw1 = 4096 + wv * 1024;

    const __bf16* kg = k + base;
    const __bf16* vg = v + base;

    // per-lane tr-read bases for V (both buffers)
    const unsigned vA0 = (unsigned)(size_t)(smem + 16384) + (unsigned)(lr * 2 + lh * 128);
    const unsigned vA1 = vA0 + 8192u;

    // Q fragments (B-operand of swapped QK^T; pre-scaled by 0.125*log2e)
    bf16x8 qf0, qf1;
    {
        const __bf16* qp = q + base + (size_t)(q0 + wv * 16 + lr) * 64 + lh * 8;
        qf0 = *(const bf16x8*)qp;
        qf1 = *(const bf16x8*)(qp + 32);
    }
    bf16x8 ones;
#pragma unroll
    for (int e = 0; e < 8; ++e) ones[e] = (__bf16)1.0f;

    f32x4 o[4] = {{0.f,0.f,0.f,0.f},{0.f,0.f,0.f,0.f},{0.f,0.f,0.f,0.f},{0.f,0.f,0.f,0.f}};
    f32x4 o4 = {0.f, 0.f, 0.f, 0.f};          // lsum accumulator (ones-MFMA)

    // prologue: stage tile 0 into buf 0
    gload16(kg + gk0, smem + lw0);
    gload16(kg + gk1, smem + lw1);
    gload16(vg + gv0, smem + 16384 + lw0);
    gload16(vg + gv1, smem + 16384 + lw1);
    __syncthreads();

    auto body = [&](const char* Kc, unsigned vA, char* kd, char* vd, int tnext) {
        // issue next-tile staging into the other buffer
        if (tnext < 64) {
            const __bf16* kp = kg + (size_t)tnext * 4096;
            const __bf16* vp = vg + (size_t)tnext * 4096;
            gload16(kp + gk0, kd + lw0);
            gload16(kp + gk1, kd + lw1);
            gload16(vp + gv0, vd + lw0);
            gload16(vp + gv1, vd + lw1);
        }

        // ---- S^T = K Q^T ----
        f32x4 s[4];
        const f32x4 z = {0.f, 0.f, 0.f, 0.f};
        __builtin_amdgcn_s_setprio(1);
#pragma unroll
        for (int fj = 0; fj < 4; ++fj) {
            int row = fj * 16 + lr;
            bf16x8 kb0 = *(const bf16x8*)(Kc + row * 128 + ((lh * 16) ^ ((row & 7) << 4)));
            bf16x8 kb1 = *(const bf16x8*)(Kc + row * 128 + (((4 + lh) * 16) ^ ((row & 7) << 4)));
            s[fj] = MFMA16(kb0, qf0, z);
            s[fj] = MFMA16(kb1, qf1, s[fj]);
        }
        __builtin_amdgcn_s_setprio(0);

        // ---- static softmax: p = exp2(s), straight into PV B-fragments ----
        bf16x8 B0, B1;
#pragma unroll
        for (int fj = 0; fj < 4; ++fj)
#pragma unroll
            for (int r = 0; r < 4; ++r) {
                float pp = __builtin_amdgcn_exp2f(s[fj][r]);
                if (fj < 2) B0[fj * 4 + r] = (__bf16)pp;
                else        B1[(fj - 2) * 4 + r] = (__bf16)pp;
            }

        // ---- O^T += V^T P ; lsum via ones-MFMA ----
        bf16x4 t0, t1, t2, t3, t4, t5, t6, t7;
        TRRM(t0, vA, "0");    TRR(t1, vA, "512");
        TRR(t2, vA, "1024");  TRR(t3, vA, "1536");
        TRR(t4, vA, "2048");  TRR(t5, vA, "2560");
        TRR(t6, vA, "3072");  TRR(t7, vA, "3584");
        asm volatile("s_waitcnt lgkmcnt(0)" ::: "memory");
        __builtin_amdgcn_sched_barrier(0);
        __builtin_amdgcn_s_setprio(1);
        o4   = MFMA16(ones, B0, o4);
        o[0] = MFMA16(SHUF8(t0, t1), B0, o[0]);
        o[0] = MFMA16(SHUF8(t2, t3), B1, o[0]);
        o[1] = MFMA16(SHUF8(t4, t5), B0, o[1]);
        o[1] = MFMA16(SHUF8(t6, t7), B1, o[1]);
        __builtin_amdgcn_s_setprio(0);
        TRR(t0, vA, "4096");  TRR(t1, vA, "4608");
        TRR(t2, vA, "5120");  TRR(t3, vA, "5632");
        TRR(t4, vA, "6144");  TRR(t5, vA, "6656");
        TRR(t6, vA, "7168");  TRR(t7, vA, "7680");
        asm volatile("s_waitcnt lgkmcnt(0)" ::: "memory");
        __builtin_amdgcn_sched_barrier(0);
        __builtin_amdgcn_s_setprio(1);
        o4   = MFMA16(ones, B1, o4);
        o[2] = MFMA16(SHUF8(t0, t1), B0, o[2]);
        o[2] = MFMA16(SHUF8(t2, t3), B1, o[2]);
        o[3] = MFMA16(SHUF8(t4, t5), B0, o[3]);
        o[3] = MFMA16(SHUF8(t6, t7), B1, o[3]);
        __builtin_amdgcn_s_setprio(0);

        __syncthreads();   // implicit vmcnt(0): staging landed; buf flip safe
    };

    for (int t = 0; t < 64; t += 2) {
        body(smem,        vA0, smem + 8192, smem + 16384 + 8192, t + 1);
        body(smem + 8192, vA1, smem,        smem + 16384,        t + 2);
    }

    // epilogue: every lane holds the full denominator in o4[0]
    float inv = 1.0f / o4[0];
    int b = bh >> 2, h = bh & 3;
    int n = q0 + wv * 16 + lr;
    __bf16* dst = ao + ((size_t)(b * 4096 + n)) * 256 + h * 64 + lh * 4;
#pragma unroll
    for (int fd = 0; fd < 4; ++fd) {
        bf16x4 pk;
#pragma unroll
        for (int r = 0; r < 4; ++r) pk[r] = (__bf16)(o[fd][r] * inv);
        *(bf16x4*)(dst + fd * 16) = pk;
    }
}

// ---------------------------------------------------------------------------
// 4) out projection + bias + residual + 1/sqrt(2), transposed store [B,C,N]
// ---------------------------------------------------------------------------
__global__ __launch_bounds__(256) void out_gemm(const __bf16* __restrict__ ao,
                                                const __bf16* __restrict__ wf,
                                                const float* __restrict__ bout,
                                                const float* __restrict__ x,
                                                float* __restrict__ out) {
    const int mt = blockIdx.x, nt = blockIdx.y;
    const int tid = threadIdx.x;
    const int w = tid >> 6, l = tid & 63;
    const int lr = l & 15, lh = l >> 4;
    f32x4 acc[4] = {{0.f,0.f,0.f,0.f},{0.f,0.f,0.f,0.f},{0.f,0.f,0.f,0.f},{0.f,0.f,0.f,0.f}};
    const __bf16* ap = ao + (size_t)(mt * 64 + w * 16 + lr) * 256 + lh * 8;
#pragma unroll
    for (int kk = 0; kk < 8; ++kk) {
        bf16x8 a = *(const bf16x8*)(ap + kk * 32);
#pragma unroll
        for (int fj = 0; fj < 4; ++fj) {
            bf16x8 bf = *(const bf16x8*)(wf + (size_t)(((nt * 4 + fj) * 8 + kk) * 64 + l) * 8);
            acc[fj] = MFMA16(a, bf, acc[fj]);
        }
    }
    __shared__ float tile[64][72];
#pragma unroll
    for (int fj = 0; fj < 4; ++fj) {
        float bias = bout[nt * 64 + fj * 16 + lr];
#pragma unroll
        for (int r = 0; r < 4; ++r)
            tile[w * 16 + lh * 4 + r][fj * 16 + lr] = acc[fj][r] + bias;
    }
    __syncthreads();
    int b  = mt >> 6;
    int n0 = (mt & 63) * 64;
    int c0 = nt * 64;
    int cl = tid >> 2, nq = tid & 3;
    size_t gbase = ((size_t)(b * 256 + c0 + cl)) * 4096 + n0 + nq * 16;
#pragma unroll
    for (int i = 0; i < 16; i += 4) {
        float4 xv = *(const float4*)(x + gbase + i);
        float4 ov;
        ov.x = (tile[nq * 16 + i + 0][cl] + xv.x) * 0.70710678118654752f;
        ov.y = (tile[nq * 16 + i + 1][cl] + xv.y) * 0.70710678118654752f;
        ov.z = (tile[nq * 16 + i + 2][cl] + xv.z) * 0.70710678118654752f;
        ov.w = (tile[nq * 16 + i + 3][cl] + xv.w) * 0.70710678118654752f;
        *(float4*)(out + gbase + i) = ov;
    }
}

// ---------------------------------------------------------------------------
extern "C" void kernel_launch(void* const* d_in, const int* in_sizes, int n_in,
                              void* d_out, int out_size, void* d_ws, size_t ws_size,
                              hipStream_t stream) {
    const float* x     = (const float*)d_in[0];
    const float* gamma = (const float*)d_in[1];
    const float* beta  = (const float*)d_in[2];
    const float* W_qkv = (const float*)d_in[3];
    const float* b_qkv = (const float*)d_in[4];
    const float* W_out = (const float*)d_in[5];
    const float* b_out = (const float*)d_in[6];
    float* out = (float*)d_out;
    char* ws = (char*)d_ws;

    __bf16* wqf   = (__bf16*)(ws + OFF_WQKV);
    __bf16* wof   = (__bf16*)(ws + OFF_WOUT);
    float2* stats = (float2*)(ws + OFF_STATS);
    __bf16* hid   = (__bf16*)(ws + OFF_HID);   // attn_out
    __bf16* qb    = (__bf16*)(ws + OFF_Q);
    __bf16* kb    = (__bf16*)(ws + OFF_K);
    __bf16* vb    = (__bf16*)(ws + OFF_V);

    pre_kernel<<<1152, 256, 0, stream>>>(x, stats, W_qkv, W_out, wqf, wof);
    qkv_gn<<<dim3(256, 3), 256, 0, stream>>>(x, gamma, beta, stats, wqf, b_qkv, qb, kb, vb);
    attn_fwd<<<dim3(64, 16), 256, 0, stream>>>(qb, kb, vb, hid);
    out_gemm<<<dim3(256, 4), 256, 0, stream>>>(hid, wof, b_out, x, out);
}